// Round 5
// baseline (123.332 us; speedup 1.0000x reference)
//
#include <hip/hip_runtime.h>
#include <math.h>

#define NW   12
#define DIM  4096
#define TPB  256

typedef float v2f __attribute__((ext_vector_type(2)));   // (re, im) -> v_pk_* f32

// DPP lane exchange (VALU, no LDS pipe). CTRL: 0xB1=XOR1, 0x4E=XOR2, 0x128=row_ror:8(=XOR8).
template<int CTRL>
__device__ __forceinline__ float fdpp(float v) {
    union { float f; int i; } u, w;
    u.f = v;
    w.i = __builtin_amdgcn_update_dpp(0, u.i, CTRL, 0xF, 0xF, false);
    return w.f;
}

// RY on register bit B (0..3 of the 16-amp register file). Packed-f32 VALU.
template<int B>
__device__ __forceinline__ void ry_reg(v2f* r, float c, v2f vps, v2f vms) {
#pragma unroll
    for (int p = 0; p < 8; ++p) {
        const int i0 = ((p >> B) << (B + 1)) | (p & ((1 << B) - 1));
        const int i1 = i0 | (1 << B);
        const v2f a = r[i0], b = r[i1];
        r[i0] = __builtin_elementwise_fma(vms, b, a * c);   // c*a - s*b
        r[i1] = __builtin_elementwise_fma(vps, a, b * c);   // s*a + c*b
    }
}

// RY via DPP partner exchange on a lane bit; vsp = splat(+s) if lane bit set else splat(-s).
template<int CTRL>
__device__ __forceinline__ void ry_dpp(v2f* r, float c, v2f vsp) {
#pragma unroll
    for (int k = 0; k < 16; ++k) {
        const v2f p = { fdpp<CTRL>(r[k].x), fdpp<CTRL>(r[k].y) };
        r[k] = __builtin_elementwise_fma(vsp, p, r[k] * c);
    }
}

__global__ __launch_bounds__(TPB, 4)
void qmnist_kernel(const float* __restrict__ x,  const float* __restrict__ W1,
                   const float* __restrict__ b1, const float* __restrict__ ryp,
                   const float* __restrict__ rzp, const float* __restrict__ W2,
                   const float* __restrict__ b2, float* __restrict__ out) {
    // Exactly 32 KiB LDS. Small arrays alias the front (state lives in
    // registers whenever they are live; barriers order every transition).
    __shared__ v2f psi[DIM];
    float* smf  = (float*)psi;
    float* wred = smf;        // 48 floats
    float* encc = smf + 48;   // 12
    float* encs = smf + 60;   // 12
    float* zfin = smf + 72;   // 12

    const int tid  = threadIdx.x;
    const int blk  = blockIdx.x;
    const int lane = tid & 63;
    const int wave = tid >> 6;

    // ---------------- phase 0: feat = x[blk] @ W1^T + b1 -> encoding angles
    float acc[NW];
#pragma unroll
    for (int w = 0; w < NW; ++w) acc[w] = 0.f;
    if (tid < 196) {                      // 784 = 196 float4
        const float4 xv = ((const float4*)(x + (size_t)blk * 784))[tid];
#pragma unroll
        for (int w = 0; w < NW; ++w) {
            const float4 wv = ((const float4*)(W1 + w * 784))[tid];
            acc[w] = fmaf(xv.x, wv.x, fmaf(xv.y, wv.y, fmaf(xv.z, wv.z, xv.w * wv.w)));
        }
    }
#pragma unroll
    for (int w = 0; w < NW; ++w) {
        float v = acc[w];
        v += __shfl_down(v, 32);
        v += __shfl_down(v, 16);
        v += __shfl_down(v, 8);
        v += __shfl_down(v, 4);
        v += __shfl_down(v, 2);
        v += __shfl_down(v, 1);
        if (lane == 0) wred[wave * NW + w] = v;
    }
    __syncthreads();
    if (tid < NW) {
        float feat = wred[tid] + wred[NW + tid] + wred[2 * NW + tid] + wred[3 * NW + tid] + b1[tid];
        float a = tanhf(feat) * 3.14159265358979323846f;
        float h = 0.5f * a;
        encc[tid] = cosf(h);
        encs[tid] = sinf(h);
    }
    __syncthreads();

    // ---------------- init product state into REGISTERS.
    // amp index y = (k<<8)|tid; bit b of y <-> wire (11-b). bits 0..7 = tid, 8..11 = k.
    float hi = 1.f;
#pragma unroll
    for (int b = 0; b < 8; ++b)
        hi *= ((tid >> b) & 1) ? encs[11 - b] : encc[11 - b];
    v2f r[16];
#pragma unroll
    for (int k = 0; k < 16; ++k) {
        float f = hi;
        f *= (k & 1) ? encs[3] : encc[3];
        f *= (k & 2) ? encs[2] : encc[2];
        f *= (k & 4) ? encs[1] : encc[1];
        f *= (k & 8) ? encs[0] : encc[0];
        r[k] = (v2f){ f, 0.f };
    }

    // ---------------- variational params.
    // Layer = RY on all 12 positions, RZ on all 12 (folds to popcount phase,
    // layout-invariant), then CNOT staircase new[y] = old[y ^ (y>>1)].
    const float ry = ryp[0], rz = rzp[0];
    const float c = cosf(0.5f * ry), s = sinf(0.5f * ry);
    const v2f vps = {  s,  s };
    const v2f vms = { -s, -s };
    const int pcT = __popc(tid);
    v2f qv[5], qp[5];                    // cis(rz*(pcT+j-6)) and i*cis(...)
#pragma unroll
    for (int j = 0; j < 5; ++j) {
        const float ang = rz * (float)(pcT + j - 6);
        const float qc = cosf(ang), qs = sinf(ang);
        qv[j] = (v2f){  qc, qs };
        qp[j] = (v2f){ -qs, qc };
    }

    // per-lane signed s (splat) for the lane-exchange RY gates
    const v2f vs0 = (lane & 1)  ? vps : vms;   // position 0, XOR1  (quad_perm)
    const v2f vs1 = (lane & 2)  ? vps : vms;   // position 1, XOR2  (quad_perm)
    const v2f vs3 = (lane & 8)  ? vps : vms;   // position 3, XOR8  (row_ror:8)
    const v2f vs5 = (lane & 32) ? vps : vms;   // position 5, XOR32 (shfl)

    // ---- RT addressing: every access = ONE base VGPR + compile-time immediate,
    // and slot low4 = 4 LANE bits on both write and read (b64 min-cycle, no
    // bank conflicts). Slot maps (bit -> amp bit):
    //  S (RT-A):  s0..3 = a0,a1,a3,a5 ; s4,5 = a2,a4 ; s6,7 = a6,a7 ; s8..11 = a8..11
    //  T (RT-C):  s0..3 = z0,z1,z3,z5 ; s4,5 = z8,z9 ; s6,7 = z2,z4 ; s8,9 = z6,z7 ; s10,11 = z10,z11
    const int t0 = tid & 1,        t1 = (tid >> 1) & 1, t2 = (tid >> 2) & 1,
              t3 = (tid >> 3) & 1, t4 = (tid >> 4) & 1, t5 = (tid >> 5) & 1;
    const int wbaseA = (tid & 3) | (t3 << 2) | (t5 << 3) | (t2 << 4) | (t4 << 5) | (tid & 192);
    const int rbaseA = (tid & 3) | (t3 << 2) | (t5 << 3) | (t2 << 8) | (t4 << 9) | ((tid & 192) << 4);
    const int wbaseC = (tid & 3) | (t3 << 2) | (t5 << 3) | (t2 << 4) | (t4 << 5) | ((tid & 192) << 4);
    const int gt = tid ^ (tid >> 1);               // gt_i = t_i ^ t_{i+1} (gt7 = t7)
    const int rbaseC0 = (gt & 1) | (((gt >> 1) & 1) << 1) | (((gt >> 3) & 1) << 2) |
                        (((gt >> 5) & 1) << 3) | (((gt >> 2) & 1) << 6) |
                        (((gt >> 4) & 1) << 7) | (((gt >> 6) & 1) << 8) | (((gt >> 7) & 1) << 9);
    const int rbaseC1 = rbaseC0 ^ 512;             // z7 = t7 ^ k0 : flip slot bit 9 when k0=1

    for (int layer = 0; layer < 3; ++layer) {
        __syncthreads();                // prior psi readers done

        // RY on positions 8-11 (register bits), canonical layout
        ry_reg<0>(r, c, vps, vms); ry_reg<1>(r, c, vps, vms);
        ry_reg<2>(r, c, vps, vms); ry_reg<3>(r, c, vps, vms);

        // RY on positions 0,1,3 via DPP (VALU), position 5 via shfl_xor
        ry_dpp<0xB1>(r, c, vs0);        // XOR1
        ry_dpp<0x4E>(r, c, vs1);        // XOR2
        ry_dpp<0x128>(r, c, vs3);       // XOR8 within row of 16
#pragma unroll
        for (int k = 0; k < 16; ++k) {
            const v2f p = { __shfl_xor(r[k].x, 32, 64), __shfl_xor(r[k].y, 32, 64) };
            r[k] = __builtin_elementwise_fma(vs5, p, r[k] * c);
        }

        // --- RT-A: store via S, read -> k' holds positions {2,4,6,7}
#pragma unroll
        for (int k = 0; k < 16; ++k)
            psi[wbaseA + (k << 8)] = r[k];
        __syncthreads();
#pragma unroll
        for (int k = 0; k < 16; ++k)
            r[k] = psi[rbaseA + (k << 4)];

        // RY on positions 2,4,6,7 (now register bits)
        ry_reg<0>(r, c, vps, vms); ry_reg<1>(r, c, vps, vms);
        ry_reg<2>(r, c, vps, vms); ry_reg<3>(r, c, vps, vms);

        // fold of all 12 RZ gates: phase by popcount (layout-invariant)
#pragma unroll
        for (int k = 0; k < 16; ++k) {
            const int j = __popc(k);    // compile-time per unrolled k
            r[k] = __builtin_elementwise_fma((v2f){ r[k].y, r[k].y }, qp[j], qv[j] * r[k].x);
        }

        // --- RT-C: store via T, CNOT gather new[y] = old[y ^ (y>>1)] back to L0
        __syncthreads();                // all RT-A reads done
#pragma unroll
        for (int k = 0; k < 16; ++k)
            psi[wbaseC + (k << 6)] = r[k];
        __syncthreads();
#pragma unroll
        for (int k = 0; k < 16; ++k) {
            const int gk   = (k ^ (k >> 1)) & 15;
            const int immC = ((gk & 3) << 4) | ((gk & 12) << 8);
            r[k] = psi[((k & 1) ? rbaseC1 : rbaseC0) + immC];
        }
    }
    __syncthreads();                    // all psi reads done before aliasing reuse

    // ---------------- measure <Z_w> from registers (canonical layout)
    float t_total = 0.f, s3 = 0.f, s2 = 0.f, s1 = 0.f, s0 = 0.f;
#pragma unroll
    for (int k = 0; k < 16; ++k) {
        const float pp = fmaf(r[k].x, r[k].x, r[k].y * r[k].y);
        t_total += pp;
        if (k & 1) s3 += pp;   // bit 8  -> wire 3
        if (k & 2) s2 += pp;   // bit 9  -> wire 2
        if (k & 4) s1 += pp;   // bit 10 -> wire 1
        if (k & 8) s0 += pp;   // bit 11 -> wire 0
    }
    float contrib[NW];
    contrib[3] = t_total - 2.f * s3;
    contrib[2] = t_total - 2.f * s2;
    contrib[1] = t_total - 2.f * s1;
    contrib[0] = t_total - 2.f * s0;
#pragma unroll
    for (int b = 0; b < 8; ++b) {
        const int w = 11 - b;                       // wires 11..4 from tid bits 0..7
        contrib[w] = ((tid >> b) & 1) ? -t_total : t_total;
    }
#pragma unroll
    for (int w = 0; w < NW; ++w) {
        float v = contrib[w];
        v += __shfl_down(v, 32);
        v += __shfl_down(v, 16);
        v += __shfl_down(v, 8);
        v += __shfl_down(v, 4);
        v += __shfl_down(v, 2);
        v += __shfl_down(v, 1);
        if (lane == 0) wred[wave * NW + w] = v;
    }
    __syncthreads();
    if (tid < NW)
        zfin[tid] = wred[tid] + wred[NW + tid] + wred[2 * NW + tid] + wred[3 * NW + tid];
    __syncthreads();

    // ---------------- head: out = z @ W2^T + b2
    if (tid < 10) {
        float o = b2[tid];
#pragma unroll
        for (int w = 0; w < NW; ++w)
            o = fmaf(zfin[w], W2[tid * NW + w], o);
        out[(size_t)blk * 10 + tid] = o;
    }
}

extern "C" void kernel_launch(void* const* d_in, const int* in_sizes, int n_in,
                              void* d_out, int out_size, void* d_ws, size_t ws_size,
                              hipStream_t stream) {
    const float* x   = (const float*)d_in[0];
    const float* W1  = (const float*)d_in[1];
    const float* b1  = (const float*)d_in[2];
    const float* ry  = (const float*)d_in[3];
    const float* rz  = (const float*)d_in[4];
    const float* W2  = (const float*)d_in[5];
    const float* b2  = (const float*)d_in[6];
    float* out = (float*)d_out;

    const int batch = in_sizes[0] / 784;   // 2048
    qmnist_kernel<<<batch, TPB, 0, stream>>>(x, W1, b1, ry, rz, W2, b2, out);
}